// Round 9
// baseline (155.710 us; speedup 1.0000x reference)
//
#include <hip/hip_runtime.h>

#define WW 512
#define HH 512
#define NPLANES 64   // B*C = 16*4
#define NCH 4
#define NSTRIP 8     // 64-row strips per plane (4 waves x 16 rows per block)

// DPP cross-lane at full VALU rate.
#define DPP_ROW_SHR1 0x111
#define DPP_ROW_SHR2 0x112
#define DPP_ROW_SHR4 0x114
#define DPP_ROW_SHR8 0x118
#define DPP_BCAST15  0x142
#define DPP_BCAST31  0x143
#define DPP_WF_SL1   0x130   // shift left 1  (lane i <- i+1), bound: lane63 -> 0
#define DPP_WF_RL1   0x134   // rotate left 1 (lane 63 <- lane 0)
#define DPP_WF_SR1   0x138   // shift right 1 (lane i <- i-1), bound: lane0 -> 0
#define DPP_WF_RR1   0x13c   // rotate right 1 (lane 0 <- lane 63)

template <int CTRL, int ROW_MASK = 0xf>
__device__ __forceinline__ float dpp_movf(float x) {
    return __int_as_float(__builtin_amdgcn_update_dpp(
        0, __float_as_int(x), CTRL, ROW_MASK, 0xf, true));
}

// full 64-lane sum; result valid in lane 63
__device__ __forceinline__ float dpp_wave_sum(float v) {
    v += dpp_movf<DPP_ROW_SHR1>(v);
    v += dpp_movf<DPP_ROW_SHR2>(v);
    v += dpp_movf<DPP_ROW_SHR4>(v);
    v += dpp_movf<DPP_ROW_SHR8>(v);
    v += dpp_movf<DPP_BCAST15, 0xa>(v);
    v += dpp_movf<DPP_BCAST31, 0xc>(v);
    return v;
}

// sigmoid((x - 0.5) * 10) = 1 / (1 + exp2(-x*10*log2e + 5*log2e))
__device__ __forceinline__ float sigf(float x) {
    float e = __builtin_amdgcn_exp2f(__builtin_fmaf(x, -14.4269504089f, 7.2134752044f));
    return __builtin_amdgcn_rcpf(1.0f + e);
}

// Load one row in split-halves layout: each dwordx4 is a contiguous 1 KB
// across the wave (lane i <- bytes 16i and 1024+16i). R1-R8 used 8
// consecutive floats/lane = 32B stride per instruction = 16 line-touches
// per load (2x the TA/L1 line-request work). R9 theory: per-CU line-request
// throughput is the wall (achieved 14 B/cy/CU ~= m13's streaming ceiling,
// invariant to waves/compute/prefetch).
__device__ __forceinline__ void load_row_sig(const float* __restrict__ rowp,
                                             int lane, float* L, float* R) {
    const float4* pl = reinterpret_cast<const float4*>(rowp) + lane;        // cols 4i..4i+3
    const float4* pr = reinterpret_cast<const float4*>(rowp + 256) + lane;  // cols 256+4i..
    float4 a = *pl, b = *pr;
    L[0]=sigf(a.x); L[1]=sigf(a.y); L[2]=sigf(a.z); L[3]=sigf(a.w);
    R[0]=sigf(b.x); R[1]=sigf(b.y); R[2]=sigf(b.z); R[3]=sigf(b.w);
}

__global__ __launch_bounds__(256, 4)
void k_stage1(const float* __restrict__ inp, const float* __restrict__ tgt,
              float* __restrict__ colpart, float* __restrict__ rowsum,
              float* __restrict__ out) {
    const int bid    = blockIdx.x;
    const int tensor = bid >> 9;          // 0..1
    const int plane  = (bid >> 3) & 63;   // 0..63
    const int s      = bid & 7;           // 0..7 (64-row strip)
    const int tid    = threadIdx.x;
    const int wave   = tid >> 6;
    const int lane   = tid & 63;

    if (bid == 0 && tid == 0) out[0] = 0.0f;  // zero-init for stage-2 atomics

    const float* __restrict__ base =
        (tensor == 0 ? inp : tgt) + (size_t)plane * (HH * WW);
    const int r0 = s * 64 + wave * 16;
    const int r1 = r0 + 16;

    float pL[4], pR[4], cL[4], cR[4], aL[4], aR[4];
    #pragma unroll
    for (int k = 0; k < 4; ++k) { aL[k] = 0.0f; aR[k] = 0.0f; }

    // prologue: prev = sig(row r0-1) (zero-pad), cur = sig(row r0)
    if (r0 == 0) {
        #pragma unroll
        for (int k = 0; k < 4; ++k) { pL[k] = 0.0f; pR[k] = 0.0f; }
    } else {
        load_row_sig(base + (size_t)(r0 - 1) * WW, lane, pL, pR);
    }
    load_row_sig(base + (size_t)r0 * WW, lane, cL, cR);

    float* __restrict__ rs_out =
        rowsum + ((size_t)tensor * NPLANES + plane) * HH;

    for (int r = r0; r < r1; ++r) {
        // 1) issue next-row loads first (raw; convert after horizontal work)
        float4 a, b;
        if (r + 1 < HH) {
            const float* rowp = base + (size_t)(r + 1) * WW;
            a = reinterpret_cast<const float4*>(rowp)[lane];
            b = reinterpret_cast<const float4*>(rowp + 256)[lane];
        } else {
            a = make_float4(0.f,0.f,0.f,0.f); b = a;
        }

        // 2) horizontal bounds on row r (split-halves neighbor exchange)
        float lvL  = dpp_movf<DPP_WF_SR1>(cL[3]);   // lane0 -> 0 (pad col -1)
        float rvLs = dpp_movf<DPP_WF_SL1>(cL[0]);   // lanes 0..62
        float seamR = dpp_movf<DPP_WF_RL1>(cR[0]);  // lane63 <- lane0 col256
        float rvL  = (lane == 63) ? seamR : rvLs;

        float lvRs = dpp_movf<DPP_WF_SR1>(cR[3]);   // lanes 1..63
        float seamL = dpp_movf<DPP_WF_RR1>(cL[3]);  // lane0 <- lane63 col255
        float lvR  = (lane == 0) ? seamL : lvRs;
        float rvR  = dpp_movf<DPP_WF_SL1>(cR[0]);   // lane63 -> 0 (pad col W)

        float hp;
        hp  = sigf(fabsf(cL[1] - lvL));
        hp += sigf(fabsf(cL[2] - cL[0]));
        hp += sigf(fabsf(cL[3] - cL[1]));
        hp += sigf(fabsf(rvL   - cL[2]));
        hp += sigf(fabsf(cR[1] - lvR));
        hp += sigf(fabsf(cR[2] - cR[0]));
        hp += sigf(fabsf(cR[3] - cR[1]));
        hp += sigf(fabsf(rvR   - cR[2]));

        float tot = dpp_wave_sum(hp);
        if (lane == 63) rs_out[r] = tot;

        // 3) convert loaded row, vertical bounds, rotate window
        float nL[4], nR[4];
        if (r + 1 < HH) {
            nL[0]=sigf(a.x); nL[1]=sigf(a.y); nL[2]=sigf(a.z); nL[3]=sigf(a.w);
            nR[0]=sigf(b.x); nR[1]=sigf(b.y); nR[2]=sigf(b.z); nR[3]=sigf(b.w);
        } else {
            #pragma unroll
            for (int k = 0; k < 4; ++k) { nL[k] = 0.0f; nR[k] = 0.0f; }
        }
        #pragma unroll
        for (int k = 0; k < 4; ++k) {
            aL[k] += sigf(fabsf(nL[k] - pL[k]));
            aR[k] += sigf(fabsf(nR[k] - pR[k]));
            pL[k] = cL[k]; cL[k] = nL[k];
            pR[k] = cR[k]; cR[k] = nR[k];
        }
    }

    // combine column partials across the 4 waves of this block (once/block)
    __shared__ float cl4[4][WW];
    #pragma unroll
    for (int k = 0; k < 4; ++k) {
        cl4[wave][4 * lane + k]       = aL[k];
        cl4[wave][256 + 4 * lane + k] = aR[k];
    }
    __syncthreads();

    float* __restrict__ cp_out =
        colpart + (((size_t)tensor * NPLANES + plane) * NSTRIP + s) * WW;
    for (int c = tid; c < WW; c += 256)
        cp_out[c] = cl4[0][c] + cl4[1][c] + cl4[2][c] + cl4[3][c];
}

// logical sobel-source value: S(0)=512*sig(0), S(j)=sum[j-1], 0 outside [0,512)
__device__ __forceinline__ float Sval(const float* s, int j, float s0) {
    if (j < 0 || j >= 512) return 0.0f;
    if (j == 0) return s0;
    return s[j - 1];
}
__device__ __forceinline__ float term(const float* s, int j, float s0) {
    return fabsf(Sval(s, j + 1, s0) - Sval(s, j - 1, s0));
}

// Stage 2 (merged with mean): one block per plane; finalize col sums,
// sobel+abs+sum both directions for both tensors, atomicAdd mean contribution.
__global__ __launch_bounds__(256)
void k_stage2(const float* __restrict__ colpart, const float* __restrict__ rowsum,
              const float* __restrict__ weight, float* __restrict__ out) {
    __shared__ float cI[WW], cT[WW], rI[WW], rT[WW];
    const int p   = blockIdx.x;   // plane = b*4 + c
    const int tid = threadIdx.x;

    for (int c = tid; c < WW; c += 256) {
        const float* a = colpart + (((size_t)0 * NPLANES + p) * NSTRIP) * WW + c;
        const float* b = colpart + (((size_t)1 * NPLANES + p) * NSTRIP) * WW + c;
        float sa = 0.f, sb = 0.f;
        #pragma unroll
        for (int i = 0; i < NSTRIP; ++i) { sa += a[i * WW]; sb += b[i * WW]; }
        cI[c] = sa;
        cT[c] = sb;
        rI[c] = rowsum[((size_t)0 * NPLANES + p) * HH + c];
        rT[c] = rowsum[((size_t)1 * NPLANES + p) * HH + c];
    }
    __syncthreads();

    // 512 * sigmoid(-5)
    const float s0 = 3.4267396732f;

    float sIx = 0.f, sTx = 0.f, sIy = 0.f, sTy = 0.f;
    for (int j = tid; j < WW; j += 256) {
        sIx += term(cI, j, s0);
        sTx += term(cT, j, s0);
        sIy += term(rI, j, s0);
        sTy += term(rT, j, s0);
    }
    #pragma unroll
    for (int off = 32; off >= 1; off >>= 1) {
        sIx += __shfl_xor(sIx, off);
        sTx += __shfl_xor(sTx, off);
        sIy += __shfl_xor(sIy, off);
        sTy += __shfl_xor(sTy, off);
    }
    __shared__ float red[4][4];
    const int wave = tid >> 6, lane = tid & 63;
    if (lane == 0) {
        red[wave][0] = sIx; red[wave][1] = sTx;
        red[wave][2] = sIy; red[wave][3] = sTy;
    }
    __syncthreads();
    if (tid == 0) {
        float Ix = 0.f, Tx = 0.f, Iy = 0.f, Ty = 0.f;
        for (int w2 = 0; w2 < 4; ++w2) {
            Ix += red[w2][0]; Tx += red[w2][1];
            Iy += red[w2][2]; Ty += red[w2][3];
        }
        Ix *= 0.25f; Tx *= 0.25f; Iy *= 0.25f; Ty *= 0.25f;
        const float wgt = weight[p & (NCH - 1)];
        float loss = 0.5f * (fabsf((Ix - Tx) * wgt) + fabsf((Iy - Ty) * wgt));
        atomicAdd(out, loss * (1.0f / NPLANES));
    }
}

extern "C" void kernel_launch(void* const* d_in, const int* in_sizes, int n_in,
                              void* d_out, int out_size, void* d_ws, size_t ws_size,
                              hipStream_t stream) {
    const float* inp = (const float*)d_in[0];
    const float* tgt = (const float*)d_in[1];
    const float* wgt = (const float*)d_in[2];
    float* ws = (float*)d_ws;

    // ws layout (floats):
    float* colpart = ws;                       // [2][64][8][512] = 524288
    float* rowsum  = ws + 524288;              // [2][64][512]    = 65536

    k_stage1<<<1024, 256, 0, stream>>>(inp, tgt, colpart, rowsum, (float*)d_out);
    k_stage2<<<64, 256, 0, stream>>>(colpart, rowsum, wgt, (float*)d_out);
}